// Round 2
// 31866.135 us; speedup vs baseline: 1.0016x; 1.0016x over previous
//
#include <hip/hip_runtime.h>
#include <math.h>

#define IN_SIZE 96
#define HID 128
#define H3 384
#define LIN_IN 32

// ---------------------------------------------------------------------------
// Kernel A (parallel): igates[t][j] = dot(input_GRU[t,:], w_ih[j,:]) + b_ih[j]
// ---------------------------------------------------------------------------
__global__ __launch_bounds__(384, 2)
void igates_kernel(const float* __restrict__ x, const float* __restrict__ w_ih,
                   const float* __restrict__ b_ih, float* __restrict__ ig, int T)
{
    const int TT = 16;
    int t0 = blockIdx.x * TT;
    int j = threadIdx.x; // 0..383
    __shared__ __align__(16) float xs[TT * IN_SIZE]; // 6 KB
    for (int idx = j; idx < TT * IN_SIZE; idx += H3)
        xs[idx] = x[(size_t)t0 * IN_SIZE + idx];
    __syncthreads();

    float acc[TT];
    float b = b_ih[j];
#pragma unroll
    for (int tt = 0; tt < TT; tt++) acc[tt] = b;

    const float4* w4 = (const float4*)(w_ih + (size_t)j * IN_SIZE);
#pragma unroll
    for (int k = 0; k < IN_SIZE / 4; k++) {
        float4 wv = w4[k];
#pragma unroll
        for (int tt = 0; tt < TT; tt++) {
            const float4* xv4 = (const float4*)(xs + tt * IN_SIZE);
            float4 xv = xv4[k];
            acc[tt] = fmaf(wv.x, xv.x, acc[tt]);
            acc[tt] = fmaf(wv.y, xv.y, acc[tt]);
            acc[tt] = fmaf(wv.z, xv.z, acc[tt]);
            acc[tt] = fmaf(wv.w, xv.w, acc[tt]);
        }
    }
#pragma unroll
    for (int tt = 0; tt < TT; tt++)
        ig[(size_t)(t0 + tt) * H3 + j] = acc[tt];
}

// ---------------------------------------------------------------------------
// Kernel B (sequential scan): one workgroup, 512 threads = 8 waves (2/SIMD).
// tid -> j = tid>>2 (hidden unit), kseg = tid&3 (32-wide k slice).
// Thread owns all three gate rows {j, j+128, j+256}; quad DPP k-combine puts
// hr,hz,hn in the kseg==0 lane which computes hnew[j]: one barrier/step.
//
// *** BEST MEASURED SHAPE (R10: 31.9 ms, 1168 cyc/step, on-CU VALU ~99%) ***
// Structural survey (R11/R14/R15/R16) all regressed:
//  - 256thr 1 wave/SIMD: no TLP, +40% (R11)
//  - 768thr: LDS return-BW saturated (196KB/step), +90% (R14)
//  - 8-way k-split + ds_swizzle combine: LDS-pipe on serial path, +43% (R15)
//  - two-phase wave-uniform gates: -165 busy but +272 idle (2nd barrier +
//    latency-exposed 2-wave gate phase), +9% (R16)
// DO NOT RESTRUCTURE. The issue port is the pole and it is saturated.
//
// *** NUMERICS ARE FROZEN — NOW INCLUDING ALL PACKED MATH (R7/R8/R17) ***
// scalar fmaf only. v_pk_fma_f32 failed THREE times:
//   - twice with absmax 0.28125 (earlier sessions, ordering unverified)
//   - once with absmax 0.234375 (R17) with PROVEN order-exact packing
//     (per-component chains + (x+y)+(z+w) association preserved bit-for-bit)
// => the VOP3P fp32 pipe itself rounds differently from scalar v_fmac_f32 on
// gfx950; any packed/dot/MFMA path diverges the chaotic 65536-step recurrence
// past the 0.215 absmax threshold. float4 accumulators, (x+y)+(z+w),
// quad_sum DPP. DO NOT TOUCH THE ARITHMETIC. DO NOT RETRY PACKED MATH.
//
// Guards: literal weight indices (R2: dynamic idx -> scratch spill);
// raw "lgkmcnt(0); s_barrier" (R4: __syncthreads drains vmcnt, kills
// prefetch); depth-2 two-set prefetch, incremental pointers (R8);
// padded h layout hs[kseg*36+off] (R3: 0 bank conflicts);
// amdgpu_waves_per_eu(2,2) (R10: 256-reg class, VGPR 88).
// ---------------------------------------------------------------------------
__device__ __forceinline__ void fma4(float4& acc, const float4& wv, const float4& hv)
{
    acc.x = fmaf(wv.x, hv.x, acc.x);
    acc.y = fmaf(wv.y, hv.y, acc.y);
    acc.z = fmaf(wv.z, hv.z, acc.z);
    acc.w = fmaf(wv.w, hv.w, acc.w);
}

__device__ __forceinline__ float quad_sum(float x)
{
    float t;
    t = __int_as_float(__builtin_amdgcn_mov_dpp(__float_as_int(x), 0xB1, 0xF, 0xF, true)); // [1,0,3,2]
    x += t;
    t = __int_as_float(__builtin_amdgcn_mov_dpp(__float_as_int(x), 0x4E, 0xF, 0xF, true)); // [2,3,0,1]
    x += t;
    return x;
}

__device__ __forceinline__ void fast_barrier()
{
    asm volatile("s_waitcnt lgkmcnt(0)\n\ts_barrier" ::: "memory");
}

#define HPAD 36  // 32 floats per k-segment + 4 pad

__global__
__attribute__((amdgpu_flat_work_group_size(512, 512), amdgpu_waves_per_eu(2, 2)))
void scan_kernel(const float* __restrict__ ig, const float* __restrict__ h0,
                 const float* __restrict__ w_hh, const float* __restrict__ b_n,
                 float* __restrict__ hlin, int T)
{
    __shared__ __align__(16) float hs[4 * HPAD];

    const int tid = threadIdx.x;     // 0..511
    const int j = tid >> 2;          // 0..127
    const int kseg = tid & 3;        // 0..3
    const bool gate_lane = (kseg == 0);

    // weights for rows j, j+128, j+256 (k slice kseg*32..+32) -> registers
    float4 w0[8], w1[8], w2[8];
    {
        const float* b0 = w_hh + (size_t)j * HID + kseg * 32;
        const float* b1 = w_hh + (size_t)(j + HID) * HID + kseg * 32;
        const float* b2 = w_hh + (size_t)(j + 2 * HID) * HID + kseg * 32;
#pragma unroll
        for (int k = 0; k < 8; k++) {
            w0[k] = ((const float4*)b0)[k];
            w1[k] = ((const float4*)b1)[k];
            w2[k] = ((const float4*)b2)[k];
        }
    }
    if (tid < HID) hs[(tid >> 5) * HPAD + (tid & 31)] = h0[tid];

    // two gate-input register sets: P0 = even step, P1 = odd step
    float bn = 0.f;
    float p00 = 0.f, p01 = 0.f, p02 = 0.f;  // set 0
    float p10 = 0.f, p11 = 0.f, p12 = 0.f;  // set 1
    if (gate_lane) {
        bn = b_n[j];
        p00 = ig[j];
        p01 = ig[HID + j];
        p02 = ig[2 * HID + j];
        const float* q = ig + H3;
        p10 = q[j];
        p11 = q[HID + j];
        p12 = q[2 * HID + j];
    }
    __syncthreads();

    const float4* hp = (const float4*)(hs + kseg * HPAD);
    const int hwidx = (j >> 5) * HPAD + (j & 31);

    // incrementally-advanced prefetch base: points at ig[(s+2)*H3 + j]
    const float* pf = ig + (size_t)2 * H3 + j;
    float* hl = hlin + j;  // hlin[step*LIN_IN + j], advanced by LIN_IN

#define MATVEC_GATES(C0, C1, C2, DO_PREFETCH)                                  \
    {                                                                          \
        float4 a0 = {0.f, 0.f, 0.f, 0.f}, a1 = a0, a2 = a0;                    \
        _Pragma("unroll")                                                      \
        for (int kk = 0; kk < 8; kk++) {                                       \
            float4 hv = hp[kk];                                                \
            fma4(a0, w0[kk], hv);                                              \
            fma4(a1, w1[kk], hv);                                              \
            fma4(a2, w2[kk], hv);                                              \
        }                                                                      \
        float s0 = (a0.x + a0.y) + (a0.z + a0.w);                              \
        float s1 = (a1.x + a1.y) + (a1.z + a1.w);                              \
        float s2 = (a2.x + a2.y) + (a2.z + a2.w);                              \
        s0 = quad_sum(s0); s1 = quad_sum(s1); s2 = quad_sum(s2);               \
        if (gate_lane) {                                                       \
            float hprev = hs[hwidx];                                           \
            float er = __expf(-(C0 + s0));                                     \
            float r = __builtin_amdgcn_rcpf(1.f + er);                         \
            float ez = __expf(-(C1 + s1));                                     \
            float z = __builtin_amdgcn_rcpf(1.f + ez);                         \
            float xn = C2 + r * (s2 + bn);                                     \
            float e2 = __expf(-2.f * fabsf(xn));                               \
            float th = (1.f - e2) * __builtin_amdgcn_rcpf(1.f + e2);           \
            float nn = copysignf(th, xn);                                      \
            float hnew = nn + z * (hprev - nn);                                \
            hs[hwidx] = hnew;                                                  \
            if (j < LIN_IN) *hl = hnew;                                        \
            if (DO_PREFETCH) {  /* refill this set for step+2 */               \
                C0 = pf[0];                                                    \
                C1 = pf[HID];                                                  \
                C2 = pf[2 * HID];                                              \
            }                                                                  \
        }                                                                      \
        hl += LIN_IN;                                                          \
        pf += H3;                                                              \
        fast_barrier();                                                        \
    }

    int s = 0;
    for (; s + 4 <= T; s += 2) {           // both halves may prefetch
        MATVEC_GATES(p00, p01, p02, true)
        MATVEC_GATES(p10, p11, p12, true)
    }
    // tail: last two steps, no prefetch (uniform, outside the hot loop)
    MATVEC_GATES(p00, p01, p02, false)
    MATVEC_GATES(p10, p11, p12, false)
#undef MATVEC_GATES
}

// ---------------------------------------------------------------------------
// Kernel C (parallel): out[t] = dot(hlin[t,:], xlin[t,:]) + lbias
// ---------------------------------------------------------------------------
__global__ __launch_bounds__(256)
void readout_kernel(const float* __restrict__ hlin, const float* __restrict__ xlin,
                    const float* __restrict__ lbias, float* __restrict__ out, int T)
{
    int gid = blockIdx.x * 256 + threadIdx.x;
    int t = gid >> 3;
    int seg = gid & 7;
    if (t < T) {
        float4 hv = ((const float4*)hlin)[(size_t)t * 8 + seg];
        float4 xv = ((const float4*)xlin)[(size_t)t * 8 + seg];
        float p = hv.x * xv.x + hv.y * xv.y + hv.z * xv.z + hv.w * xv.w;
        p += __shfl_xor(p, 1);
        p += __shfl_xor(p, 2);
        p += __shfl_xor(p, 4);
        if (seg == 0) out[t] = p + lbias[0];
    }
}

extern "C" void kernel_launch(void* const* d_in, const int* in_sizes, int n_in,
                              void* d_out, int out_size, void* d_ws, size_t ws_size,
                              hipStream_t stream) {
    const float* x_gru = (const float*)d_in[0];  // (T, 96)
    const float* x_lin = (const float*)d_in[1];  // (T, 32)
    const float* h0    = (const float*)d_in[2];  // (128,)
    const float* w_ih  = (const float*)d_in[3];  // (384, 96)
    const float* w_hh  = (const float*)d_in[4];  // (384, 128)
    const float* b_ih  = (const float*)d_in[5];  // (384,)
    const float* b_n   = (const float*)d_in[6];  // (128,)
    const float* lbias = (const float*)d_in[7];  // (1,)
    float* out = (float*)d_out;                  // (T, 1)

    int T = in_sizes[0] / IN_SIZE;               // 65536 (even)
    float* igates = (float*)d_ws;                    // T*384 floats = 96 MiB
    float* hlin   = (float*)d_ws + (size_t)T * H3;   // T*32 floats  =  8 MiB

    igates_kernel<<<T / 16, 384, 0, stream>>>(x_gru, w_ih, b_ih, igates, T);
    scan_kernel<<<1, 512, 0, stream>>>(igates, h0, w_hh, b_n, hlin, T);
    readout_kernel<<<(T * 8 + 255) / 256, 256, 0, stream>>>(hlin, x_lin, lbias, out, T);
}